// Round 6
// baseline (528.184 us; speedup 1.0000x reference)
//
#include <hip/hip_runtime.h>
#include <math.h>

#define B_ 8
#define N_ 1024
#define C_ 320
#define H_ 5
#define D_ 64
#define M_ (B_*N_)
#define TM 16

typedef unsigned short ushort_t;
typedef __attribute__((ext_vector_type(8))) short bf16x8;
typedef __attribute__((ext_vector_type(4))) float f32x4;

struct Gauss {
  float u[H_][7];   // 1D gaussian (normalized)
  float au[H_][7];  // alpha * u
};

// fp32 -> bf16 RNE (manual, version-stable)
__device__ __forceinline__ ushort_t f2b(float f) {
  union { float f; unsigned u; } c; c.f = f;
  unsigned r = c.u + 0x7fffu + ((c.u >> 16) & 1u);
  return (ushort_t)(r >> 16);
}
__device__ __forceinline__ float b2f(ushort_t u) {
  union { float f; unsigned u; } c; c.u = ((unsigned)u) << 16;
  return c.f;
}

// ---------------- LayerNorm: one wave per row ----------------
__global__ __launch_bounds__(64) void ln_kernel(const float* __restrict__ x,
    const float* __restrict__ gamma, const float* __restrict__ beta,
    float* __restrict__ xn) {
  int row = blockIdx.x;
  int lane = threadIdx.x;
  const float* xr = x + (long)row * C_;
  float vals[5];
  float s = 0.f, ss = 0.f;
#pragma unroll
  for (int j = 0; j < 5; ++j) {
    float vv = xr[lane + 64*j];
    vals[j] = vv; s += vv; ss += vv*vv;
  }
#pragma unroll
  for (int o = 32; o > 0; o >>= 1) {
    s  += __shfl_xor(s, o, 64);
    ss += __shfl_xor(ss, o, 64);
  }
  float mean = s * (1.0f/C_);
  float var  = ss * (1.0f/C_) - mean*mean;
  float rstd = rsqrtf(var + 1e-5f);
  float* outr = xn + (long)row * C_;
#pragma unroll
  for (int j = 0; j < 5; ++j) {
    int c = lane + 64*j;
    outr[c] = (vals[j]-mean)*rstd*gamma[c] + beta[c];
  }
}

// ---------------- QKV GEMM (8192x320 @ 320x960^T) + scatter ----------------
// q (pre-scaled by d^-0.5) and k stored bf16 in (B,H,N,d); v TRANSPOSED bf16 vt[bh][d][n]
__global__ __launch_bounds__(256) void qkv_kernel(const float* __restrict__ xn,
    const float* __restrict__ w, const float* __restrict__ bias,
    ushort_t* __restrict__ q, ushort_t* __restrict__ k, ushort_t* __restrict__ vt) {
  __shared__ float As[16][68];
  __shared__ float Bs[16][68];
  int j0 = blockIdx.x * 64;
  int m0 = blockIdx.y * 64;
  int tid = threadIdx.x;
  int tx = tid & 15, ty = tid >> 4;
  int lr = tid >> 2;
  int lc = (tid & 3) << 2;
  float acc[4][4] = {};
  for (int kk = 0; kk < C_; kk += 16) {
    float4 a4 = *(const float4*)(xn + (long)(m0+lr)*C_ + kk + lc);
    float4 b4 = *(const float4*)(w  + (long)(j0+lr)*C_ + kk + lc);
    As[lc+0][lr]=a4.x; As[lc+1][lr]=a4.y; As[lc+2][lr]=a4.z; As[lc+3][lr]=a4.w;
    Bs[lc+0][lr]=b4.x; Bs[lc+1][lr]=b4.y; Bs[lc+2][lr]=b4.z; Bs[lc+3][lr]=b4.w;
    __syncthreads();
#pragma unroll
    for (int p = 0; p < 16; ++p) {
      float4 av = *(const float4*)&As[p][ty<<2];
      float4 bv = *(const float4*)&Bs[p][tx<<2];
      float aa[4] = {av.x,av.y,av.z,av.w};
      float bb[4] = {bv.x,bv.y,bv.z,bv.w};
#pragma unroll
      for (int i=0;i<4;++i)
#pragma unroll
        for (int j=0;j<4;++j) acc[i][j] += aa[i]*bb[j];
    }
    __syncthreads();
  }
#pragma unroll
  for (int i=0;i<4;++i) {
    int m = m0 + (ty<<2) + i;
    int bb2 = m >> 10, n = m & (N_-1);
#pragma unroll
    for (int j=0;j<4;++j) {
      int col = j0 + (tx<<2) + j;
      float val = acc[i][j] + bias[col];
      int three = col / 320;
      int rem = col - three*320;
      int h = rem >> 6, dd = rem & 63;
      if (three == 0) {
        q[(((long)bb2*H_ + h)*N_ + n)*D_ + dd] = f2b(val * 0.125f);  // fold d^-0.5
      } else if (three == 1) {
        k[(((long)bb2*H_ + h)*N_ + n)*D_ + dd] = f2b(val);
      } else {
        vt[(((long)bb2*H_ + h)*D_ + dd)*N_ + n] = f2b(val);
      }
    }
  }
}

// ---------------- QK^T per (b,h) via MFMA bf16: 128x128 tile / block ----------------
__global__ __launch_bounds__(256, 4) void qk_kernel(const ushort_t* __restrict__ q,
    const ushort_t* __restrict__ kmat, ushort_t* __restrict__ attn) {
  __shared__ __align__(16) ushort_t Qs[128][72];  // +8 pad: 2-way bank alias (free)
  __shared__ __align__(16) ushort_t Ks[128][72];
  int bh = blockIdx.z;
  int m0 = blockIdx.x * 128;   // query rows
  int n0 = blockIdx.y * 128;   // key cols
  int tid = threadIdx.x;
  int lane = tid & 63, wv = tid >> 6;
  int l16 = lane & 15, qd = lane >> 4;
  const ushort_t* qb = q    + ((long)bh*N_ + m0)*D_;
  const ushort_t* kb = kmat + ((long)bh*N_ + n0)*D_;
#pragma unroll
  for (int i = 0; i < 4; ++i) {
    int chunk = tid + 256*i;            // 1024 chunks of 8 bf16
    int row = chunk >> 3, c8 = (chunk & 7) << 3;
    *(uint4*)&Qs[row][c8] = *(const uint4*)(qb + (long)row*D_ + c8);
    *(uint4*)&Ks[row][c8] = *(const uint4*)(kb + (long)row*D_ + c8);
  }
  __syncthreads();
  f32x4 acc[2][8];
#pragma unroll
  for (int i=0;i<2;++i)
#pragma unroll
    for (int j=0;j<8;++j) acc[i][j] = (f32x4){0.f,0.f,0.f,0.f};
#pragma unroll
  for (int ks = 0; ks < 2; ++ks) {
    int k0 = ks*32 + qd*8;
    bf16x8 a0 = *(const bf16x8*)&Qs[wv*32 + l16][k0];
    bf16x8 a1 = *(const bf16x8*)&Qs[wv*32 + 16 + l16][k0];
#pragma unroll
    for (int ct = 0; ct < 8; ++ct) {
      bf16x8 b = *(const bf16x8*)&Ks[ct*16 + l16][k0];
      acc[0][ct] = __builtin_amdgcn_mfma_f32_16x16x32_bf16(a0, b, acc[0][ct], 0,0,0);
      acc[1][ct] = __builtin_amdgcn_mfma_f32_16x16x32_bf16(a1, b, acc[1][ct], 0,0,0);
    }
  }
  ushort_t* ob = attn + ((long)bh*N_ + m0 + wv*32)*N_ + n0;
#pragma unroll
  for (int rt = 0; rt < 2; ++rt)
#pragma unroll
    for (int r = 0; r < 4; ++r) {
      long rowoff = (long)(rt*16 + qd*4 + r)*N_;
#pragma unroll
      for (int ct = 0; ct < 8; ++ct)
        ob[rowoff + ct*16 + l16] = f2b(acc[rt][ct][r]);
    }
}

// ------- Fused separable blur + softmax + MFMA PV (spill-proof delay-line) -------
// VGPR history: (1024,8) bound -> cap 32, 1.1 GB spill; no bound / (1024,4)
// min-only bound -> backend targets LDS-allowed 8 waves/EU, cap 64, 400 MB
// spill. amdgpu_waves_per_eu(4,4) pins BOTH ends -> 128-VGPR budget, no spill.
__global__ __launch_bounds__(1024)
__attribute__((amdgpu_waves_per_eu(4, 4)))
void bsp_kernel(
    const ushort_t* __restrict__ attn, const ushort_t* __restrict__ vt,
    float* __restrict__ ao, Gauss gw) {
  __shared__ ushort_t P[TM][1032];    // bf16 exp(logits); +8 pad for A-frag banking
  __shared__ float scratch[4096];     // [0..2047] dbuf rowbuf | [2048..2559] reductions | PV partials
  __shared__ float bmax[TM], bsum[TM];

  int bh = blockIdx.y;
  int h = bh % H_;
  int n0 = blockIdx.x * TM;
  int tid = threadIdx.x;
  int m = tid;
  int lane = tid & 63, wv = tid >> 6;
  const ushort_t* ab = attn + (long)bh*N_*N_;

  // block-uniform coefficients -> SGPRs
  float u0 = gw.u[h][0], u1 = gw.u[h][1], u2 = gw.u[h][2], u3 = gw.u[h][3],
        u4 = gw.u[h][4], u5 = gw.u[h][5], u6 = gw.u[h][6];
  float au0 = gw.au[h][0], au1 = gw.au[h][1], au2 = gw.au[h][2], au3 = gw.au[h][3],
        au4 = gw.au[h][4], au5 = gw.au[h][5], au6 = gw.au[h][6];

  // column-neighbor indices with reflect (named scalars: no dynamic indexing)
  int nb0 = m >= 3 ? m-3 : 3-m;
  int nb1 = m >= 2 ? m-2 : 2-m;
  int nb2 = m >= 1 ? m-1 : 1-m;
  int nb3 = m;
  int nb4 = m+1 <= N_-1 ? m+1 : 2*(N_-1)-(m+1);
  int nb5 = m+2 <= N_-1 ? m+2 : 2*(N_-1)-(m+2);
  int nb6 = m+3 <= N_-1 ? m+3 : 2*(N_-1)-(m+3);

  float rbw0=0,rbw1=0,rbw2=0,rbw3=0,rbw4=0,rbw5=0,rbw6=0;  // rb delay line
  float vd0=0,vd1=0,vd2=0,vd3=0;                            // raw-val delay line
  float lg[16];
  float vcur, vnxt = 0.f;
  {
    int p = n0 - 3;
    int rr = p < 0 ? -p : p;
    vcur = b2f(ab[(long)rr*N_ + m]);
  }

#define BSP_STEP(s, EMIT) \
  { \
    if ((s) < 21) { \
      int pn = n0 - 2 + (s); \
      int rn = pn < 0 ? -pn : (pn > N_-1 ? 2*(N_-1)-pn : pn); \
      vnxt = b2f(ab[(long)rn*N_ + m]); \
    } \
    scratch[((s)&1)*1024 + m] = vcur; \
    __syncthreads(); \
    { \
      const float* rbp = &scratch[((s)&1)*1024]; \
      float rb = u0*rbp[nb0] + u1*rbp[nb1] + u2*rbp[nb2] + u3*rbp[nb3] \
               + u4*rbp[nb4] + u5*rbp[nb5] + u6*rbp[nb6]; \
      rbw0=rbw1; rbw1=rbw2; rbw2=rbw3; rbw3=rbw4; rbw4=rbw5; rbw5=rbw6; rbw6=rb; \
    } \
    vd0=vd1; vd1=vd2; vd2=vd3; vd3=vcur; \
    vcur = vnxt; \
    EMIT \
  }
#define BSP_EMIT(r) lg[r] = vd0 + au0*rbw0+au1*rbw1+au2*rbw2+au3*rbw3+au4*rbw4+au5*rbw5+au6*rbw6;

  BSP_STEP(0, )
  BSP_STEP(1, )
  BSP_STEP(2, )
  BSP_STEP(3, )
  BSP_STEP(4, )
  BSP_STEP(5, )
  BSP_STEP(6,  BSP_EMIT(0))
  BSP_STEP(7,  BSP_EMIT(1))
  BSP_STEP(8,  BSP_EMIT(2))
  BSP_STEP(9,  BSP_EMIT(3))
  BSP_STEP(10, BSP_EMIT(4))
  BSP_STEP(11, BSP_EMIT(5))
  BSP_STEP(12, BSP_EMIT(6))
  BSP_STEP(13, BSP_EMIT(7))
  BSP_STEP(14, BSP_EMIT(8))
  BSP_STEP(15, BSP_EMIT(9))
  BSP_STEP(16, BSP_EMIT(10))
  BSP_STEP(17, BSP_EMIT(11))
  BSP_STEP(18, BSP_EMIT(12))
  BSP_STEP(19, BSP_EMIT(13))
  BSP_STEP(20, BSP_EMIT(14))
  BSP_STEP(21, BSP_EMIT(15))
#undef BSP_STEP
#undef BSP_EMIT

  // ---- softmax over m (block-wide, batched for 16 rows) ----
#pragma unroll
  for (int r = 0; r < TM; ++r) {
    float mx = lg[r];
#pragma unroll
    for (int o = 32; o > 0; o >>= 1) mx = fmaxf(mx, __shfl_xor(mx, o, 64));
    if (lane == 0) scratch[2048 + wv*16 + r] = mx;
  }
  __syncthreads();
  if (tid < 16) {
    float mx = -1e30f;
#pragma unroll
    for (int ww = 0; ww < 16; ++ww) mx = fmaxf(mx, scratch[2048 + ww*16 + tid]);
    bmax[tid] = mx;
  }
  __syncthreads();
#pragma unroll
  for (int r = 0; r < TM; ++r) {
    float e = __expf(lg[r] - bmax[r]);
    P[r][m] = f2b(e);
    lg[r] = e;
  }
#pragma unroll
  for (int r = 0; r < TM; ++r) {
    float sm = lg[r];
#pragma unroll
    for (int o = 32; o > 0; o >>= 1) sm += __shfl_xor(sm, o, 64);
    if (lane == 0) scratch[2304 + wv*16 + r] = sm;
  }
  __syncthreads();
  if (tid < 16) {
    float sm = 0.f;
#pragma unroll
    for (int ww = 0; ww < 16; ++ww) sm += scratch[2304 + ww*16 + tid];
    bsum[tid] = sm;
  }
  __syncthreads();   // P + bsum ready; scratch free for PV partials

  // ---- PV via MFMA: out[16][64] = P[16][1024] @ V[1024][64] ----
  int dt = wv & 3, kc = wv >> 2;
  int qd = lane >> 4, l16 = lane & 15;
  f32x4 pvacc = {0.f, 0.f, 0.f, 0.f};
  const ushort_t* vtb = vt + ((long)bh*D_ + dt*16 + l16)*N_;
#pragma unroll
  for (int s = 0; s < 8; ++s) {
    int k0 = kc*256 + s*32 + qd*8;
    bf16x8 afrag = *(const bf16x8*)&P[l16][k0];
    bf16x8 bfrag = *(const bf16x8*)(vtb + k0);
    pvacc = __builtin_amdgcn_mfma_f32_16x16x32_bf16(afrag, bfrag, pvacc, 0, 0, 0);
  }
  if (kc > 0) {
    *(f32x4*)(scratch + ((kc-1)*4 + dt)*256 + lane*4) = pvacc;
  }
  __syncthreads();
  if (kc == 0) {
#pragma unroll
    for (int j = 0; j < 3; ++j) {
      f32x4 o = *(const f32x4*)(scratch + (j*4 + dt)*256 + lane*4);
      pvacc += o;
    }
#pragma unroll
    for (int r = 0; r < 4; ++r) {
      int row = qd*4 + r;
      ao[((long)bh*N_ + n0 + row)*D_ + dt*16 + l16] = pvacc[r] / bsum[row];
    }
  }
}

// ---------------- proj GEMM (8192x320 @ 320x320^T), gathered A ----------------
__global__ __launch_bounds__(256) void proj_kernel(const float* __restrict__ ao,
    const float* __restrict__ w, const float* __restrict__ bias,
    float* __restrict__ out) {
  __shared__ float As[16][68];
  __shared__ float Bs[16][68];
  int j0 = blockIdx.x * 64;
  int m0 = blockIdx.y * 64;
  int tid = threadIdx.x;
  int tx = tid & 15, ty = tid >> 4;
  int lr = tid >> 2;
  int lc = (tid & 3) << 2;
  int m = m0 + lr;
  int bb2 = m >> 10, n = m & (N_-1);
  float acc[4][4] = {};
  for (int kk = 0; kk < C_; kk += 16) {
    int kcol = kk + lc;
    int h = kcol >> 6, dd = kcol & 63;
    float4 a4 = *(const float4*)(ao + (((long)bb2*H_ + h)*N_ + n)*D_ + dd);
    float4 b4 = *(const float4*)(w + (long)(j0+lr)*C_ + kcol);
    As[lc+0][lr]=a4.x; As[lc+1][lr]=a4.y; As[lc+2][lr]=a4.z; As[lc+3][lr]=a4.w;
    Bs[lc+0][lr]=b4.x; Bs[lc+1][lr]=b4.y; Bs[lc+2][lr]=b4.z; Bs[lc+3][lr]=b4.w;
    __syncthreads();
#pragma unroll
    for (int p = 0; p < 16; ++p) {
      float4 av = *(const float4*)&As[p][ty<<2];
      float4 bv = *(const float4*)&Bs[p][tx<<2];
      float aa[4] = {av.x,av.y,av.z,av.w};
      float bb[4] = {bv.x,bv.y,bv.z,bv.w};
#pragma unroll
      for (int i=0;i<4;++i)
#pragma unroll
        for (int j=0;j<4;++j) acc[i][j] += aa[i]*bb[j];
    }
    __syncthreads();
  }
#pragma unroll
  for (int i=0;i<4;++i) {
    int mm = m0 + (ty<<2) + i;
    float* orow = out + (long)mm*C_ + j0 + (tx<<2);
    float4 bi = *(const float4*)(bias + j0 + (tx<<2));
    float4 st = make_float4(acc[i][0]+bi.x, acc[i][1]+bi.y,
                            acc[i][2]+bi.z, acc[i][3]+bi.w);
    *(float4*)orow = st;
  }
}

extern "C" void kernel_launch(void* const* d_in, const int* in_sizes, int n_in,
                              void* d_out, int out_size, void* d_ws, size_t ws_size,
                              hipStream_t stream) {
  const float* x      = (const float*)d_in[0];
  const float* ln_g   = (const float*)d_in[1];
  const float* ln_b   = (const float*)d_in[2];
  const float* qkv_w  = (const float*)d_in[3];
  const float* qkv_b  = (const float*)d_in[4];
  const float* proj_w = (const float*)d_in[5];
  const float* proj_b = (const float*)d_in[6];
  float* out = (float*)d_out;

  char* ws = (char*)d_ws;
  const long sz_bhnd = (long)B_*H_*N_*D_;   // 2,621,440
  float*    xn   = (float*)ws;                      ws += (long)M_*C_*4;
  float*    ao   = (float*)ws;                      ws += sz_bhnd*4;
  ushort_t* q    = (ushort_t*)ws;                   ws += sz_bhnd*2;
  ushort_t* k    = (ushort_t*)ws;                   ws += sz_bhnd*2;
  ushort_t* vt   = (ushort_t*)ws;                   ws += sz_bhnd*2;
  ushort_t* attn = (ushort_t*)ws;                   // 40*1024*1024*2 B = 84 MB

  // Host-side 1D Gaussian kernels (separable: K = outer(u,u))
  Gauss gw;
  const float sig[H_] = {1.f, 2.f, 3.f, 4.f, 5.f};
  for (int h = 0; h < H_; ++h) {
    float g[7], s = 0.f;
    for (int t = 0; t < 7; ++t) {
      float xx = (float)(t - 3);
      g[t] = expf(-xx*xx / (2.f*sig[h]*sig[h]));
      s += g[t];
    }
    float alpha = 0.1f * (float)(h+1);
    for (int t = 0; t < 7; ++t) {
      gw.u[h][t]  = g[t] / s;
      gw.au[h][t] = alpha * g[t] / s;
    }
  }

  ln_kernel<<<M_, 64, 0, stream>>>(x, ln_g, ln_b, xn);
  qkv_kernel<<<dim3(15, 128), 256, 0, stream>>>(xn, qkv_w, qkv_b, q, k, vt);
  qk_kernel<<<dim3(8, 8, B_*H_), 256, 0, stream>>>(q, k, attn);
  bsp_kernel<<<dim3(N_/TM, B_*H_), 1024, 0, stream>>>(attn, vt, ao, gw);
  proj_kernel<<<dim3(5, 128), 256, 0, stream>>>(ao, proj_w, proj_b, out);
}

// Round 7
// 527.990 us; speedup vs baseline: 1.0004x; 1.0004x over previous
//
#include <hip/hip_runtime.h>
#include <math.h>

#define B_ 8
#define N_ 1024
#define C_ 320
#define H_ 5
#define D_ 64
#define M_ (B_*N_)
#define TM 16

typedef unsigned short ushort_t;
typedef __attribute__((ext_vector_type(8))) short bf16x8;
typedef __attribute__((ext_vector_type(4))) float f32x4;

// fp32 -> bf16 RNE (manual, version-stable)
__device__ __forceinline__ ushort_t f2b(float f) {
  union { float f; unsigned u; } c; c.f = f;
  unsigned r = c.u + 0x7fffu + ((c.u >> 16) & 1u);
  return (ushort_t)(r >> 16);
}
__device__ __forceinline__ float b2f(ushort_t u) {
  union { float f; unsigned u; } c; c.u = ((unsigned)u) << 16;
  return c.f;
}
// force a block-uniform float into an SGPR (frees VGPR pressure)
__device__ __forceinline__ float uni(float v) {
  union { float f; int i; } c; c.f = v;
  c.i = __builtin_amdgcn_readfirstlane(c.i);
  return c.f;
}

// ---------------- LayerNorm: one wave per row ----------------
__global__ __launch_bounds__(64) void ln_kernel(const float* __restrict__ x,
    const float* __restrict__ gamma, const float* __restrict__ beta,
    float* __restrict__ xn) {
  int row = blockIdx.x;
  int lane = threadIdx.x;
  const float* xr = x + (long)row * C_;
  float vals[5];
  float s = 0.f, ss = 0.f;
#pragma unroll
  for (int j = 0; j < 5; ++j) {
    float vv = xr[lane + 64*j];
    vals[j] = vv; s += vv; ss += vv*vv;
  }
#pragma unroll
  for (int o = 32; o > 0; o >>= 1) {
    s  += __shfl_xor(s, o, 64);
    ss += __shfl_xor(ss, o, 64);
  }
  float mean = s * (1.0f/C_);
  float var  = ss * (1.0f/C_) - mean*mean;
  float rstd = rsqrtf(var + 1e-5f);
  float* outr = xn + (long)row * C_;
#pragma unroll
  for (int j = 0; j < 5; ++j) {
    int c = lane + 64*j;
    outr[c] = (vals[j]-mean)*rstd*gamma[c] + beta[c];
  }
}

// ---------------- QKV GEMM (8192x320 @ 320x960^T) + scatter ----------------
// q (pre-scaled by d^-0.5) and k stored bf16 in (B,H,N,d); v TRANSPOSED bf16 vt[bh][d][n]
__global__ __launch_bounds__(256) void qkv_kernel(const float* __restrict__ xn,
    const float* __restrict__ w, const float* __restrict__ bias,
    ushort_t* __restrict__ q, ushort_t* __restrict__ k, ushort_t* __restrict__ vt) {
  __shared__ float As[16][68];
  __shared__ float Bs[16][68];
  int j0 = blockIdx.x * 64;
  int m0 = blockIdx.y * 64;
  int tid = threadIdx.x;
  int tx = tid & 15, ty = tid >> 4;
  int lr = tid >> 2;
  int lc = (tid & 3) << 2;
  float acc[4][4] = {};
  for (int kk = 0; kk < C_; kk += 16) {
    float4 a4 = *(const float4*)(xn + (long)(m0+lr)*C_ + kk + lc);
    float4 b4 = *(const float4*)(w  + (long)(j0+lr)*C_ + kk + lc);
    As[lc+0][lr]=a4.x; As[lc+1][lr]=a4.y; As[lc+2][lr]=a4.z; As[lc+3][lr]=a4.w;
    Bs[lc+0][lr]=b4.x; Bs[lc+1][lr]=b4.y; Bs[lc+2][lr]=b4.z; Bs[lc+3][lr]=b4.w;
    __syncthreads();
#pragma unroll
    for (int p = 0; p < 16; ++p) {
      float4 av = *(const float4*)&As[p][ty<<2];
      float4 bv = *(const float4*)&Bs[p][tx<<2];
      float aa[4] = {av.x,av.y,av.z,av.w};
      float bb[4] = {bv.x,bv.y,bv.z,bv.w};
#pragma unroll
      for (int i=0;i<4;++i)
#pragma unroll
        for (int j=0;j<4;++j) acc[i][j] += aa[i]*bb[j];
    }
    __syncthreads();
  }
#pragma unroll
  for (int i=0;i<4;++i) {
    int m = m0 + (ty<<2) + i;
    int bb2 = m >> 10, n = m & (N_-1);
#pragma unroll
    for (int j=0;j<4;++j) {
      int col = j0 + (tx<<2) + j;
      float val = acc[i][j] + bias[col];
      int three = col / 320;
      int rem = col - three*320;
      int h = rem >> 6, dd = rem & 63;
      if (three == 0) {
        q[(((long)bb2*H_ + h)*N_ + n)*D_ + dd] = f2b(val * 0.125f);  // fold d^-0.5
      } else if (three == 1) {
        k[(((long)bb2*H_ + h)*N_ + n)*D_ + dd] = f2b(val);
      } else {
        vt[(((long)bb2*H_ + h)*D_ + dd)*N_ + n] = f2b(val);
      }
    }
  }
}

// ---------------- QK^T per (b,h) via MFMA bf16: 128x128 tile / block ----------------
__global__ __launch_bounds__(256, 4) void qk_kernel(const ushort_t* __restrict__ q,
    const ushort_t* __restrict__ kmat, ushort_t* __restrict__ attn) {
  __shared__ __align__(16) ushort_t Qs[128][72];  // +8 pad: 2-way bank alias (free)
  __shared__ __align__(16) ushort_t Ks[128][72];
  int bh = blockIdx.z;
  int m0 = blockIdx.x * 128;   // query rows
  int n0 = blockIdx.y * 128;   // key cols
  int tid = threadIdx.x;
  int lane = tid & 63, wv = tid >> 6;
  int l16 = lane & 15, qd = lane >> 4;
  const ushort_t* qb = q    + ((long)bh*N_ + m0)*D_;
  const ushort_t* kb = kmat + ((long)bh*N_ + n0)*D_;
#pragma unroll
  for (int i = 0; i < 4; ++i) {
    int chunk = tid + 256*i;            // 1024 chunks of 8 bf16
    int row = chunk >> 3, c8 = (chunk & 7) << 3;
    *(uint4*)&Qs[row][c8] = *(const uint4*)(qb + (long)row*D_ + c8);
    *(uint4*)&Ks[row][c8] = *(const uint4*)(kb + (long)row*D_ + c8);
  }
  __syncthreads();
  f32x4 acc[2][8];
#pragma unroll
  for (int i=0;i<2;++i)
#pragma unroll
    for (int j=0;j<8;++j) acc[i][j] = (f32x4){0.f,0.f,0.f,0.f};
#pragma unroll
  for (int ks = 0; ks < 2; ++ks) {
    int k0 = ks*32 + qd*8;
    bf16x8 a0 = *(const bf16x8*)&Qs[wv*32 + l16][k0];
    bf16x8 a1 = *(const bf16x8*)&Qs[wv*32 + 16 + l16][k0];
#pragma unroll
    for (int ct = 0; ct < 8; ++ct) {
      bf16x8 b = *(const bf16x8*)&Ks[ct*16 + l16][k0];
      acc[0][ct] = __builtin_amdgcn_mfma_f32_16x16x32_bf16(a0, b, acc[0][ct], 0,0,0);
      acc[1][ct] = __builtin_amdgcn_mfma_f32_16x16x32_bf16(a1, b, acc[1][ct], 0,0,0);
    }
  }
  ushort_t* ob = attn + ((long)bh*N_ + m0 + wv*32)*N_ + n0;
#pragma unroll
  for (int rt = 0; rt < 2; ++rt)
#pragma unroll
    for (int r = 0; r < 4; ++r) {
      long rowoff = (long)(rt*16 + qd*4 + r)*N_;
#pragma unroll
      for (int ct = 0; ct < 8; ++ct)
        ob[rowoff + ct*16 + l16] = f2b(acc[rt][ct][r]);
    }
}

// ------- Fused separable blur + softmax + MFMA PV -------
// Spill history: the 400 MB/dispatch scratch traffic (R2-R6) was the Gauss
// kernarg struct demoted to stack by dynamic indexing gw.u[h][t] (runtime h
// blocks SROA). Fix: no struct — compute the 7 taps in-kernel from h
// (sigma = h+1, alpha = 0.1*(h+1)) and readfirstlane them into SGPRs.
__global__ __launch_bounds__(1024) void bsp_kernel(
    const ushort_t* __restrict__ attn, const ushort_t* __restrict__ vt,
    float* __restrict__ ao) {
  __shared__ ushort_t P[TM][1032];    // bf16 exp(logits); +8 pad for A-frag banking
  __shared__ float scratch[4096];     // [0..2047] dbuf rowbuf | [2048..2559] reductions | PV partials
  __shared__ float bmax[TM], bsum[TM];

  int bh = blockIdx.y;
  int h = bh % H_;
  int n0 = blockIdx.x * TM;
  int tid = threadIdx.x;
  int m = tid;
  int lane = tid & 63, wv = tid >> 6;
  const ushort_t* ab = attn + (long)bh*N_*N_;

  // In-kernel Gaussian taps (symmetric): g_t = exp(-t^2/(2 sigma^2)), u = g/sum
  float sigma = (float)(h + 1);
  float ei = -1.f / (2.f * sigma * sigma);
  float g0 = expf(9.f*ei), g1 = expf(4.f*ei), g2 = expf(1.f*ei);
  float isum = 1.f / (2.f*(g0 + g1 + g2) + 1.f);
  float alpha = 0.1f * sigma;
  float u0 = uni(g0*isum), u1 = uni(g1*isum), u2 = uni(g2*isum), u3 = uni(isum);
  float u4 = u2, u5 = u1, u6 = u0;
  float au0 = uni(alpha*g0*isum), au1 = uni(alpha*g1*isum),
        au2 = uni(alpha*g2*isum), au3 = uni(alpha*isum);
  float au4 = au2, au5 = au1, au6 = au0;

  // column-neighbor indices with reflect (named scalars: no dynamic indexing)
  int nb0 = m >= 3 ? m-3 : 3-m;
  int nb1 = m >= 2 ? m-2 : 2-m;
  int nb2 = m >= 1 ? m-1 : 1-m;
  int nb3 = m;
  int nb4 = m+1 <= N_-1 ? m+1 : 2*(N_-1)-(m+1);
  int nb5 = m+2 <= N_-1 ? m+2 : 2*(N_-1)-(m+2);
  int nb6 = m+3 <= N_-1 ? m+3 : 2*(N_-1)-(m+3);

  float rbw0=0,rbw1=0,rbw2=0,rbw3=0,rbw4=0,rbw5=0,rbw6=0;  // rb delay line
  float vd0=0,vd1=0,vd2=0,vd3=0;                            // raw-val delay line
  float lg[16];
  float vcur, vnxt = 0.f;
  {
    int p = n0 - 3;
    int rr = p < 0 ? -p : p;
    vcur = b2f(ab[(long)rr*N_ + m]);
  }

#define BSP_STEP(s, EMIT) \
  { \
    if ((s) < 21) { \
      int pn = n0 - 2 + (s); \
      int rn = pn < 0 ? -pn : (pn > N_-1 ? 2*(N_-1)-pn : pn); \
      vnxt = b2f(ab[(long)rn*N_ + m]); \
    } \
    scratch[((s)&1)*1024 + m] = vcur; \
    __syncthreads(); \
    { \
      const float* rbp = &scratch[((s)&1)*1024]; \
      float rb = u0*rbp[nb0] + u1*rbp[nb1] + u2*rbp[nb2] + u3*rbp[nb3] \
               + u4*rbp[nb4] + u5*rbp[nb5] + u6*rbp[nb6]; \
      rbw0=rbw1; rbw1=rbw2; rbw2=rbw3; rbw3=rbw4; rbw4=rbw5; rbw5=rbw6; rbw6=rb; \
    } \
    vd0=vd1; vd1=vd2; vd2=vd3; vd3=vcur; \
    vcur = vnxt; \
    EMIT \
  }
#define BSP_EMIT(r) lg[r] = vd0 + au0*rbw0+au1*rbw1+au2*rbw2+au3*rbw3+au4*rbw4+au5*rbw5+au6*rbw6;

  BSP_STEP(0, )
  BSP_STEP(1, )
  BSP_STEP(2, )
  BSP_STEP(3, )
  BSP_STEP(4, )
  BSP_STEP(5, )
  BSP_STEP(6,  BSP_EMIT(0))
  BSP_STEP(7,  BSP_EMIT(1))
  BSP_STEP(8,  BSP_EMIT(2))
  BSP_STEP(9,  BSP_EMIT(3))
  BSP_STEP(10, BSP_EMIT(4))
  BSP_STEP(11, BSP_EMIT(5))
  BSP_STEP(12, BSP_EMIT(6))
  BSP_STEP(13, BSP_EMIT(7))
  BSP_STEP(14, BSP_EMIT(8))
  BSP_STEP(15, BSP_EMIT(9))
  BSP_STEP(16, BSP_EMIT(10))
  BSP_STEP(17, BSP_EMIT(11))
  BSP_STEP(18, BSP_EMIT(12))
  BSP_STEP(19, BSP_EMIT(13))
  BSP_STEP(20, BSP_EMIT(14))
  BSP_STEP(21, BSP_EMIT(15))
#undef BSP_STEP
#undef BSP_EMIT

  // ---- softmax over m (block-wide, batched for 16 rows) ----
#pragma unroll
  for (int r = 0; r < TM; ++r) {
    float mx = lg[r];
#pragma unroll
    for (int o = 32; o > 0; o >>= 1) mx = fmaxf(mx, __shfl_xor(mx, o, 64));
    if (lane == 0) scratch[2048 + wv*16 + r] = mx;
  }
  __syncthreads();
  if (tid < 16) {
    float mx = -1e30f;
#pragma unroll
    for (int ww = 0; ww < 16; ++ww) mx = fmaxf(mx, scratch[2048 + ww*16 + tid]);
    bmax[tid] = mx;
  }
  __syncthreads();
#pragma unroll
  for (int r = 0; r < TM; ++r) {
    float e = __expf(lg[r] - bmax[r]);
    P[r][m] = f2b(e);
    lg[r] = e;
  }
#pragma unroll
  for (int r = 0; r < TM; ++r) {
    float sm = lg[r];
#pragma unroll
    for (int o = 32; o > 0; o >>= 1) sm += __shfl_xor(sm, o, 64);
    if (lane == 0) scratch[2304 + wv*16 + r] = sm;
  }
  __syncthreads();
  if (tid < 16) {
    float sm = 0.f;
#pragma unroll
    for (int ww = 0; ww < 16; ++ww) sm += scratch[2304 + ww*16 + tid];
    bsum[tid] = sm;
  }
  __syncthreads();   // P + bsum ready; scratch free for PV partials

  // ---- PV via MFMA: out[16][64] = P[16][1024] @ V[1024][64] ----
  int dt = wv & 3, kc = wv >> 2;
  int qd = lane >> 4, l16 = lane & 15;
  f32x4 pvacc = {0.f, 0.f, 0.f, 0.f};
  const ushort_t* vtb = vt + ((long)bh*D_ + dt*16 + l16)*N_;
#pragma unroll
  for (int s = 0; s < 8; ++s) {
    int k0 = kc*256 + s*32 + qd*8;
    bf16x8 afrag = *(const bf16x8*)&P[l16][k0];
    bf16x8 bfrag = *(const bf16x8*)(vtb + k0);
    pvacc = __builtin_amdgcn_mfma_f32_16x16x32_bf16(afrag, bfrag, pvacc, 0, 0, 0);
  }
  if (kc > 0) {
    *(f32x4*)(scratch + ((kc-1)*4 + dt)*256 + lane*4) = pvacc;
  }
  __syncthreads();
  if (kc == 0) {
#pragma unroll
    for (int j = 0; j < 3; ++j) {
      f32x4 o = *(const f32x4*)(scratch + (j*4 + dt)*256 + lane*4);
      pvacc += o;
    }
#pragma unroll
    for (int r = 0; r < 4; ++r) {
      int row = qd*4 + r;
      ao[((long)bh*N_ + n0 + row)*D_ + dt*16 + l16] = pvacc[r] / bsum[row];
    }
  }
}

// ---------------- proj GEMM (8192x320 @ 320x320^T), gathered A ----------------
__global__ __launch_bounds__(256) void proj_kernel(const float* __restrict__ ao,
    const float* __restrict__ w, const float* __restrict__ bias,
    float* __restrict__ out) {
  __shared__ float As[16][68];
  __shared__ float Bs[16][68];
  int j0 = blockIdx.x * 64;
  int m0 = blockIdx.y * 64;
  int tid = threadIdx.x;
  int tx = tid & 15, ty = tid >> 4;
  int lr = tid >> 2;
  int lc = (tid & 3) << 2;
  int m = m0 + lr;
  int bb2 = m >> 10, n = m & (N_-1);
  float acc[4][4] = {};
  for (int kk = 0; kk < C_; kk += 16) {
    int kcol = kk + lc;
    int h = kcol >> 6, dd = kcol & 63;
    float4 a4 = *(const float4*)(ao + (((long)bb2*H_ + h)*N_ + n)*D_ + dd);
    float4 b4 = *(const float4*)(w + (long)(j0+lr)*C_ + kcol);
    As[lc+0][lr]=a4.x; As[lc+1][lr]=a4.y; As[lc+2][lr]=a4.z; As[lc+3][lr]=a4.w;
    Bs[lc+0][lr]=b4.x; Bs[lc+1][lr]=b4.y; Bs[lc+2][lr]=b4.z; Bs[lc+3][lr]=b4.w;
    __syncthreads();
#pragma unroll
    for (int p = 0; p < 16; ++p) {
      float4 av = *(const float4*)&As[p][ty<<2];
      float4 bv = *(const float4*)&Bs[p][tx<<2];
      float aa[4] = {av.x,av.y,av.z,av.w};
      float bb[4] = {bv.x,bv.y,bv.z,bv.w};
#pragma unroll
      for (int i=0;i<4;++i)
#pragma unroll
        for (int j=0;j<4;++j) acc[i][j] += aa[i]*bb[j];
    }
    __syncthreads();
  }
#pragma unroll
  for (int i=0;i<4;++i) {
    int mm = m0 + (ty<<2) + i;
    float* orow = out + (long)mm*C_ + j0 + (tx<<2);
    float4 bi = *(const float4*)(bias + j0 + (tx<<2));
    float4 st = make_float4(acc[i][0]+bi.x, acc[i][1]+bi.y,
                            acc[i][2]+bi.z, acc[i][3]+bi.w);
    *(float4*)orow = st;
  }
}

extern "C" void kernel_launch(void* const* d_in, const int* in_sizes, int n_in,
                              void* d_out, int out_size, void* d_ws, size_t ws_size,
                              hipStream_t stream) {
  const float* x      = (const float*)d_in[0];
  const float* ln_g   = (const float*)d_in[1];
  const float* ln_b   = (const float*)d_in[2];
  const float* qkv_w  = (const float*)d_in[3];
  const float* qkv_b  = (const float*)d_in[4];
  const float* proj_w = (const float*)d_in[5];
  const float* proj_b = (const float*)d_in[6];
  float* out = (float*)d_out;

  char* ws = (char*)d_ws;
  const long sz_bhnd = (long)B_*H_*N_*D_;   // 2,621,440
  float*    xn   = (float*)ws;                      ws += (long)M_*C_*4;
  float*    ao   = (float*)ws;                      ws += sz_bhnd*4;
  ushort_t* q    = (ushort_t*)ws;                   ws += sz_bhnd*2;
  ushort_t* k    = (ushort_t*)ws;                   ws += sz_bhnd*2;
  ushort_t* vt   = (ushort_t*)ws;                   ws += sz_bhnd*2;
  ushort_t* attn = (ushort_t*)ws;                   // 40*1024*1024*2 B = 84 MB

  ln_kernel<<<M_, 64, 0, stream>>>(x, ln_g, ln_b, xn);
  qkv_kernel<<<dim3(15, 128), 256, 0, stream>>>(xn, qkv_w, qkv_b, q, k, vt);
  qk_kernel<<<dim3(8, 8, B_*H_), 256, 0, stream>>>(q, k, attn);
  bsp_kernel<<<dim3(N_/TM, B_*H_), 1024, 0, stream>>>(attn, vt, ao);
  proj_kernel<<<dim3(5, 128), 256, 0, stream>>>(ao, proj_w, proj_b, out);
}

// Round 8
// 337.023 us; speedup vs baseline: 1.5672x; 1.5666x over previous
//
#include <hip/hip_runtime.h>
#include <math.h>

#define B_ 8
#define N_ 1024
#define C_ 320
#define H_ 5
#define D_ 64
#define M_ (B_*N_)
#define TM 16

typedef unsigned short ushort_t;
typedef __attribute__((ext_vector_type(8))) short bf16x8;
typedef __attribute__((ext_vector_type(4))) float f32x4;

// fp32 -> bf16 RNE (manual, version-stable)
__device__ __forceinline__ ushort_t f2b(float f) {
  union { float f; unsigned u; } c; c.f = f;
  unsigned r = c.u + 0x7fffu + ((c.u >> 16) & 1u);
  return (ushort_t)(r >> 16);
}
__device__ __forceinline__ float b2f(ushort_t u) {
  union { float f; unsigned u; } c; c.u = ((unsigned)u) << 16;
  return c.f;
}
// force a block-uniform float into an SGPR (frees VGPR pressure)
__device__ __forceinline__ float uni(float v) {
  union { float f; int i; } c; c.f = v;
  c.i = __builtin_amdgcn_readfirstlane(c.i);
  return c.f;
}

// ---------------- LayerNorm: one wave per row ----------------
__global__ __launch_bounds__(64) void ln_kernel(const float* __restrict__ x,
    const float* __restrict__ gamma, const float* __restrict__ beta,
    float* __restrict__ xn) {
  int row = blockIdx.x;
  int lane = threadIdx.x;
  const float* xr = x + (long)row * C_;
  float vals[5];
  float s = 0.f, ss = 0.f;
#pragma unroll
  for (int j = 0; j < 5; ++j) {
    float vv = xr[lane + 64*j];
    vals[j] = vv; s += vv; ss += vv*vv;
  }
#pragma unroll
  for (int o = 32; o > 0; o >>= 1) {
    s  += __shfl_xor(s, o, 64);
    ss += __shfl_xor(ss, o, 64);
  }
  float mean = s * (1.0f/C_);
  float var  = ss * (1.0f/C_) - mean*mean;
  float rstd = rsqrtf(var + 1e-5f);
  float* outr = xn + (long)row * C_;
#pragma unroll
  for (int j = 0; j < 5; ++j) {
    int c = lane + 64*j;
    outr[c] = (vals[j]-mean)*rstd*gamma[c] + beta[c];
  }
}

// ---------------- QKV GEMM (8192x320 @ 320x960^T) + scatter ----------------
// q (pre-scaled by d^-0.5) and k stored bf16 in (B,H,N,d); v TRANSPOSED bf16 vt[bh][d][n]
__global__ __launch_bounds__(256) void qkv_kernel(const float* __restrict__ xn,
    const float* __restrict__ w, const float* __restrict__ bias,
    ushort_t* __restrict__ q, ushort_t* __restrict__ k, ushort_t* __restrict__ vt) {
  __shared__ float As[16][68];
  __shared__ float Bs[16][68];
  int j0 = blockIdx.x * 64;
  int m0 = blockIdx.y * 64;
  int tid = threadIdx.x;
  int tx = tid & 15, ty = tid >> 4;
  int lr = tid >> 2;
  int lc = (tid & 3) << 2;
  float acc[4][4] = {};
  for (int kk = 0; kk < C_; kk += 16) {
    float4 a4 = *(const float4*)(xn + (long)(m0+lr)*C_ + kk + lc);
    float4 b4 = *(const float4*)(w  + (long)(j0+lr)*C_ + kk + lc);
    As[lc+0][lr]=a4.x; As[lc+1][lr]=a4.y; As[lc+2][lr]=a4.z; As[lc+3][lr]=a4.w;
    Bs[lc+0][lr]=b4.x; Bs[lc+1][lr]=b4.y; Bs[lc+2][lr]=b4.z; Bs[lc+3][lr]=b4.w;
    __syncthreads();
#pragma unroll
    for (int p = 0; p < 16; ++p) {
      float4 av = *(const float4*)&As[p][ty<<2];
      float4 bv = *(const float4*)&Bs[p][tx<<2];
      float aa[4] = {av.x,av.y,av.z,av.w};
      float bb[4] = {bv.x,bv.y,bv.z,bv.w};
#pragma unroll
      for (int i=0;i<4;++i)
#pragma unroll
        for (int j=0;j<4;++j) acc[i][j] += aa[i]*bb[j];
    }
    __syncthreads();
  }
#pragma unroll
  for (int i=0;i<4;++i) {
    int m = m0 + (ty<<2) + i;
    int bb2 = m >> 10, n = m & (N_-1);
#pragma unroll
    for (int j=0;j<4;++j) {
      int col = j0 + (tx<<2) + j;
      float val = acc[i][j] + bias[col];
      int three = col / 320;
      int rem = col - three*320;
      int h = rem >> 6, dd = rem & 63;
      if (three == 0) {
        q[(((long)bb2*H_ + h)*N_ + n)*D_ + dd] = f2b(val * 0.125f);  // fold d^-0.5
      } else if (three == 1) {
        k[(((long)bb2*H_ + h)*N_ + n)*D_ + dd] = f2b(val);
      } else {
        vt[(((long)bb2*H_ + h)*D_ + dd)*N_ + n] = f2b(val);
      }
    }
  }
}

// ---------------- QK^T per (b,h) via MFMA bf16: 128x128 tile / block ----------------
__global__ __launch_bounds__(256, 4) void qk_kernel(const ushort_t* __restrict__ q,
    const ushort_t* __restrict__ kmat, ushort_t* __restrict__ attn) {
  __shared__ __align__(16) ushort_t Qs[128][72];  // +8 pad: 2-way bank alias (free)
  __shared__ __align__(16) ushort_t Ks[128][72];
  int bh = blockIdx.z;
  int m0 = blockIdx.x * 128;   // query rows
  int n0 = blockIdx.y * 128;   // key cols
  int tid = threadIdx.x;
  int lane = tid & 63, wv = tid >> 6;
  int l16 = lane & 15, qd = lane >> 4;
  const ushort_t* qb = q    + ((long)bh*N_ + m0)*D_;
  const ushort_t* kb = kmat + ((long)bh*N_ + n0)*D_;
#pragma unroll
  for (int i = 0; i < 4; ++i) {
    int chunk = tid + 256*i;            // 1024 chunks of 8 bf16
    int row = chunk >> 3, c8 = (chunk & 7) << 3;
    *(uint4*)&Qs[row][c8] = *(const uint4*)(qb + (long)row*D_ + c8);
    *(uint4*)&Ks[row][c8] = *(const uint4*)(kb + (long)row*D_ + c8);
  }
  __syncthreads();
  f32x4 acc[2][8];
#pragma unroll
  for (int i=0;i<2;++i)
#pragma unroll
    for (int j=0;j<8;++j) acc[i][j] = (f32x4){0.f,0.f,0.f,0.f};
#pragma unroll
  for (int ks = 0; ks < 2; ++ks) {
    int k0 = ks*32 + qd*8;
    bf16x8 a0 = *(const bf16x8*)&Qs[wv*32 + l16][k0];
    bf16x8 a1 = *(const bf16x8*)&Qs[wv*32 + 16 + l16][k0];
#pragma unroll
    for (int ct = 0; ct < 8; ++ct) {
      bf16x8 b = *(const bf16x8*)&Ks[ct*16 + l16][k0];
      acc[0][ct] = __builtin_amdgcn_mfma_f32_16x16x32_bf16(a0, b, acc[0][ct], 0,0,0);
      acc[1][ct] = __builtin_amdgcn_mfma_f32_16x16x32_bf16(a1, b, acc[1][ct], 0,0,0);
    }
  }
  ushort_t* ob = attn + ((long)bh*N_ + m0 + wv*32)*N_ + n0;
#pragma unroll
  for (int rt = 0; rt < 2; ++rt)
#pragma unroll
    for (int r = 0; r < 4; ++r) {
      long rowoff = (long)(rt*16 + qd*4 + r)*N_;
#pragma unroll
      for (int ct = 0; ct < 8; ++ct)
        ob[rowoff + ct*16 + l16] = f2b(acc[rt][ct][r]);
    }
}

// ------- Fused separable blur + softmax + MFMA PV, v4 -------
// R2-R7 structure spilled ~160 KB/block (22-step unroll kept lg[16]+delay
// lines live across 22 barriers; scheduler hoisted 22 indep global loads) and
// issued ~390 scalar DS ops/thread. v4: col-blur -> row-blur via LDS with
// aligned b128 vector access, logits-only register state (~45 VGPRs), 5
// barriers, ~70 DS ops/thread.
__global__ __launch_bounds__(1024) void bsp_kernel(
    const ushort_t* __restrict__ attn, const ushort_t* __restrict__ vt,
    float* __restrict__ ao) {
  __shared__ __align__(16) ushort_t raw[22][1024];   // 45,056 B  bf16 halo rows
  __shared__ __align__(16) float    cb[16][1040];    // 66,560 B  col-blur, gi=m+8, ghosts [5..7],[1032..1034]
  __shared__ __align__(16) ushort_t P[16][1032];     // 33,024 B  bf16 exp(logits)
  __shared__ float redm[16][2], reds[16][2], bsum[16];

  int bh = blockIdx.y;
  int h = bh % H_;
  int n0 = blockIdx.x * TM;
  int tid = threadIdx.x;
  int lane = tid & 63, wv = tid >> 6;
  const ushort_t* ab = attn + (long)bh*N_*N_;

  // In-kernel Gaussian taps (sigma = h+1, alpha = 0.1*(h+1)); SGPR-pinned
  float sigma = (float)(h + 1);
  float ei = -1.f / (2.f * sigma * sigma);
  float ga = expf(9.f*ei), gb = expf(4.f*ei), gc = expf(1.f*ei);
  float isum = 1.f / (2.f*(ga + gb + gc) + 1.f);
  float alpha = 0.1f * sigma;
  float u0 = uni(ga*isum), u1 = uni(gb*isum), u2 = uni(gc*isum), u3 = uni(isum);
  float au0 = uni(alpha*u0), au1 = uni(alpha*u1), au2 = uni(alpha*u2), au3 = uni(alpha*u3);
  const float uw[7] = {u0, u1, u2, u3, u2, u1, u0};
  const float aw[7] = {au0, au1, au2, au3, au2, au1, au0};

  // ---- stage 1: load 22 halo rows (reflect) as aligned 16B chunks ----
#pragma unroll
  for (int i = 0; i < 3; ++i) {
    int c = tid + 1024*i;
    if (c < 2816) {                       // 22 rows * 128 chunks
      int pr = c >> 7;
      int c8 = (c & 127) << 3;
      int p = n0 - 3 + pr;
      int rr = p < 0 ? -p : (p > N_-1 ? 2*(N_-1)-p : p);
      *(uint4*)&raw[pr][c8] = *(const uint4*)(ab + (long)rr*N_ + c8);
    }
  }
  __syncthreads();

  // ---- stage 2: column blur (vertical, all-aligned vector reads) ----
#pragma unroll
  for (int i = 0; i < 2; ++i) {
    int t = tid + 1024*i;                 // 16 rows * 128 col-groups
    int row = t >> 7;
    int cg = t & 127;
    int m0c = cg << 3;
    float v[8] = {0.f,0.f,0.f,0.f,0.f,0.f,0.f,0.f};
#pragma unroll
    for (int dy = 0; dy < 7; ++dy) {
      uint4 rwv = *(const uint4*)&raw[row + dy][m0c];
      const ushort_t* rs = (const ushort_t*)&rwv;
      float wdy = uw[dy];
#pragma unroll
      for (int j = 0; j < 8; ++j) v[j] += wdy * b2f(rs[j]);
    }
    *(float4*)&cb[row][m0c + 8]  = make_float4(v[0], v[1], v[2], v[3]);
    *(float4*)&cb[row][m0c + 12] = make_float4(v[4], v[5], v[6], v[7]);
    if (cg == 0)   { cb[row][7] = v[1]; cb[row][6] = v[2]; cb[row][5] = v[3]; }
    if (cg == 127) { cb[row][1032] = v[6]; cb[row][1033] = v[5]; cb[row][1034] = v[4]; }
  }
  __syncthreads();

  // ---- stage 3: row blur + center -> 16 logits in registers ----
  int o = tid >> 7;                       // 0..7: owns rows 2o, 2o+1
  int cg = tid & 127;
  int m0c = cg << 3;
  float lgA[8], lgB[8];
#pragma unroll
  for (int half = 0; half < 2; ++half) {
    int r = 2*o + half;
    float c[16];
#pragma unroll
    for (int qq = 0; qq < 4; ++qq) {
      float4 cc = *(const float4*)&cb[r][m0c + 4 + 4*qq];
      c[4*qq+0] = cc.x; c[4*qq+1] = cc.y; c[4*qq+2] = cc.z; c[4*qq+3] = cc.w;
    }
    uint4 rwv = *(const uint4*)&raw[r + 3][m0c];
    const ushort_t* rs = (const ushort_t*)&rwv;
    float* lg = half ? lgB : lgA;
#pragma unroll
    for (int j = 0; j < 8; ++j) {
      float s = b2f(rs[j]);
#pragma unroll
      for (int t = 0; t < 7; ++t) s += aw[t] * c[1 + j + t];
      lg[j] = s;
    }
  }

  // ---- softmax: in-register 8-reduce + wave shfl + 2-wave combine ----
  float lmA = lgA[0], lmB = lgB[0];
#pragma unroll
  for (int j = 1; j < 8; ++j) { lmA = fmaxf(lmA, lgA[j]); lmB = fmaxf(lmB, lgB[j]); }
#pragma unroll
  for (int off2 = 32; off2 > 0; off2 >>= 1) {
    lmA = fmaxf(lmA, __shfl_xor(lmA, off2, 64));
    lmB = fmaxf(lmB, __shfl_xor(lmB, off2, 64));
  }
  int wv2 = (tid >> 6) & 1;
  if (lane == 0) { redm[2*o][wv2] = lmA; redm[2*o+1][wv2] = lmB; }
  __syncthreads();
  float bmA = fmaxf(redm[2*o][0], redm[2*o][1]);
  float bmB = fmaxf(redm[2*o+1][0], redm[2*o+1][1]);
  float smA = 0.f, smB = 0.f;
  unsigned pkA[4], pkB[4];
#pragma unroll
  for (int jj = 0; jj < 4; ++jj) {
    float eA0 = __expf(lgA[2*jj]   - bmA);
    float eA1 = __expf(lgA[2*jj+1] - bmA);
    float eB0 = __expf(lgB[2*jj]   - bmB);
    float eB1 = __expf(lgB[2*jj+1] - bmB);
    smA += eA0 + eA1; smB += eB0 + eB1;
    pkA[jj] = (unsigned)f2b(eA0) | ((unsigned)f2b(eA1) << 16);
    pkB[jj] = (unsigned)f2b(eB0) | ((unsigned)f2b(eB1) << 16);
  }
  *(uint4*)&P[2*o][m0c]   = make_uint4(pkA[0], pkA[1], pkA[2], pkA[3]);
  *(uint4*)&P[2*o+1][m0c] = make_uint4(pkB[0], pkB[1], pkB[2], pkB[3]);
#pragma unroll
  for (int off2 = 32; off2 > 0; off2 >>= 1) {
    smA += __shfl_xor(smA, off2, 64);
    smB += __shfl_xor(smB, off2, 64);
  }
  if (lane == 0) { reds[2*o][wv2] = smA; reds[2*o+1][wv2] = smB; }
  __syncthreads();                        // P + reds visible
  if (tid < 16) bsum[tid] = reds[tid][0] + reds[tid][1];

  // ---- PV via MFMA: out[16][64] = P[16][1024] @ V[1024][64] ----
  int dt = wv & 3, kc = wv >> 2;
  int qd = lane >> 4, l16 = lane & 15;
  f32x4 pvacc = {0.f, 0.f, 0.f, 0.f};
  const ushort_t* vtb = vt + ((long)bh*D_ + dt*16 + l16)*N_;
#pragma unroll
  for (int s = 0; s < 8; ++s) {
    int k0 = kc*256 + s*32 + qd*8;
    bf16x8 afrag = *(const bf16x8*)&P[l16][k0];
    bf16x8 bfrag = *(const bf16x8*)(vtb + k0);
    pvacc = __builtin_amdgcn_mfma_f32_16x16x32_bf16(afrag, bfrag, pvacc, 0, 0, 0);
  }
  float* pvscr = (float*)&cb[0][0];       // cb dead after stage 3
  if (kc > 0) {
    *(f32x4*)(pvscr + ((kc-1)*4 + dt)*256 + lane*4) = pvacc;
  }
  __syncthreads();                        // partials + bsum visible
  if (kc == 0) {
#pragma unroll
    for (int j = 0; j < 3; ++j) {
      f32x4 oth = *(const f32x4*)(pvscr + (j*4 + dt)*256 + lane*4);
      pvacc += oth;
    }
#pragma unroll
    for (int r = 0; r < 4; ++r) {
      int row = qd*4 + r;
      ao[((long)bh*N_ + n0 + row)*D_ + dt*16 + l16] = pvacc[r] / bsum[row];
    }
  }
}

// ---------------- proj GEMM (8192x320 @ 320x320^T), gathered A ----------------
__global__ __launch_bounds__(256) void proj_kernel(const float* __restrict__ ao,
    const float* __restrict__ w, const float* __restrict__ bias,
    float* __restrict__ out) {
  __shared__ float As[16][68];
  __shared__ float Bs[16][68];
  int j0 = blockIdx.x * 64;
  int m0 = blockIdx.y * 64;
  int tid = threadIdx.x;
  int tx = tid & 15, ty = tid >> 4;
  int lr = tid >> 2;
  int lc = (tid & 3) << 2;
  int m = m0 + lr;
  int bb2 = m >> 10, n = m & (N_-1);
  float acc[4][4] = {};
  for (int kk = 0; kk < C_; kk += 16) {
    int kcol = kk + lc;
    int h = kcol >> 6, dd = kcol & 63;
    float4 a4 = *(const float4*)(ao + (((long)bb2*H_ + h)*N_ + n)*D_ + dd);
    float4 b4 = *(const float4*)(w + (long)(j0+lr)*C_ + kcol);
    As[lc+0][lr]=a4.x; As[lc+1][lr]=a4.y; As[lc+2][lr]=a4.z; As[lc+3][lr]=a4.w;
    Bs[lc+0][lr]=b4.x; Bs[lc+1][lr]=b4.y; Bs[lc+2][lr]=b4.z; Bs[lc+3][lr]=b4.w;
    __syncthreads();
#pragma unroll
    for (int p = 0; p < 16; ++p) {
      float4 av = *(const float4*)&As[p][ty<<2];
      float4 bv = *(const float4*)&Bs[p][tx<<2];
      float aa[4] = {av.x,av.y,av.z,av.w};
      float bb[4] = {bv.x,bv.y,bv.z,bv.w};
#pragma unroll
      for (int i=0;i<4;++i)
#pragma unroll
        for (int j=0;j<4;++j) acc[i][j] += aa[i]*bb[j];
    }
    __syncthreads();
  }
#pragma unroll
  for (int i=0;i<4;++i) {
    int mm = m0 + (ty<<2) + i;
    float* orow = out + (long)mm*C_ + j0 + (tx<<2);
    float4 bi = *(const float4*)(bias + j0 + (tx<<2));
    float4 st = make_float4(acc[i][0]+bi.x, acc[i][1]+bi.y,
                            acc[i][2]+bi.z, acc[i][3]+bi.w);
    *(float4*)orow = st;
  }
}

extern "C" void kernel_launch(void* const* d_in, const int* in_sizes, int n_in,
                              void* d_out, int out_size, void* d_ws, size_t ws_size,
                              hipStream_t stream) {
  const float* x      = (const float*)d_in[0];
  const float* ln_g   = (const float*)d_in[1];
  const float* ln_b   = (const float*)d_in[2];
  const float* qkv_w  = (const float*)d_in[3];
  const float* qkv_b  = (const float*)d_in[4];
  const float* proj_w = (const float*)d_in[5];
  const float* proj_b = (const float*)d_in[6];
  float* out = (float*)d_out;

  char* ws = (char*)d_ws;
  const long sz_bhnd = (long)B_*H_*N_*D_;   // 2,621,440
  float*    xn   = (float*)ws;                      ws += (long)M_*C_*4;
  float*    ao   = (float*)ws;                      ws += sz_bhnd*4;
  ushort_t* q    = (ushort_t*)ws;                   ws += sz_bhnd*2;
  ushort_t* k    = (ushort_t*)ws;                   ws += sz_bhnd*2;
  ushort_t* vt   = (ushort_t*)ws;                   ws += sz_bhnd*2;
  ushort_t* attn = (ushort_t*)ws;                   // 40*1024*1024*2 B = 84 MB

  ln_kernel<<<M_, 64, 0, stream>>>(x, ln_g, ln_b, xn);
  qkv_kernel<<<dim3(15, 128), 256, 0, stream>>>(xn, qkv_w, qkv_b, q, k, vt);
  qk_kernel<<<dim3(8, 8, B_*H_), 256, 0, stream>>>(q, k, attn);
  bsp_kernel<<<dim3(N_/TM, B_*H_), 1024, 0, stream>>>(attn, vt, ao);
  proj_kernel<<<dim3(5, 128), 256, 0, stream>>>(ao, proj_w, proj_b, out);
}

// Round 9
// 205.424 us; speedup vs baseline: 2.5712x; 1.6406x over previous
//
#include <hip/hip_runtime.h>
#include <math.h>

#define B_ 8
#define N_ 1024
#define C_ 320
#define H_ 5
#define D_ 64
#define M_ (B_*N_)
#define TM 16

typedef unsigned short ushort_t;
typedef __attribute__((ext_vector_type(8))) short bf16x8;
typedef __attribute__((ext_vector_type(4))) float f32x4;

// fp32 -> bf16 RNE (manual, version-stable)
__device__ __forceinline__ ushort_t f2b(float f) {
  union { float f; unsigned u; } c; c.f = f;
  unsigned r = c.u + 0x7fffu + ((c.u >> 16) & 1u);
  return (ushort_t)(r >> 16);
}
__device__ __forceinline__ float b2f(ushort_t u) {
  union { float f; unsigned u; } c; c.u = ((unsigned)u) << 16;
  return c.f;
}
// force a block-uniform float into an SGPR
__device__ __forceinline__ float uni(float v) {
  union { float f; int i; } c; c.f = v;
  c.i = __builtin_amdgcn_readfirstlane(c.i);
  return c.f;
}

// ---------------- fp32 -> bf16 weight conversion ----------------
__global__ __launch_bounds__(256) void cvt_kernel(const float* __restrict__ a,
    ushort_t* __restrict__ o, int n) {
  int idx = (blockIdx.x*256 + threadIdx.x)*8;
  if (idx < n) {
    float4 x0 = *(const float4*)(a+idx);
    float4 x1 = *(const float4*)(a+idx+4);
    ushort_t pk[8] = {f2b(x0.x),f2b(x0.y),f2b(x0.z),f2b(x0.w),
                      f2b(x1.x),f2b(x1.y),f2b(x1.z),f2b(x1.w)};
    *(uint4*)(o+idx) = *(const uint4*)pk;
  }
}

// ---------------- LayerNorm: one wave per row, bf16 out ----------------
__global__ __launch_bounds__(64) void ln_kernel(const float* __restrict__ x,
    const float* __restrict__ gamma, const float* __restrict__ beta,
    ushort_t* __restrict__ xnb) {
  int row = blockIdx.x;
  int lane = threadIdx.x;
  const float* xr = x + (long)row * C_;
  float vals[5];
  float s = 0.f, ss = 0.f;
#pragma unroll
  for (int j = 0; j < 5; ++j) {
    float vv = xr[lane + 64*j];
    vals[j] = vv; s += vv; ss += vv*vv;
  }
#pragma unroll
  for (int o = 32; o > 0; o >>= 1) {
    s  += __shfl_xor(s, o, 64);
    ss += __shfl_xor(ss, o, 64);
  }
  float mean = s * (1.0f/C_);
  float var  = ss * (1.0f/C_) - mean*mean;
  float rstd = rsqrtf(var + 1e-5f);
  ushort_t* outr = xnb + (long)row * C_;
#pragma unroll
  for (int j = 0; j < 5; ++j) {
    int c = lane + 64*j;
    outr[c] = f2b((vals[j]-mean)*rstd*gamma[c] + beta[c]);
  }
}

// ---------------- QKV GEMM via MFMA bf16: 128(M)x64(N) tile ----------------
// out[m][col] = sum_k xnb[m][k]*w[col][k] + bias[col]; col block-uniform segment.
// q (pre-scaled) / k bf16 (B,H,N,d); v transposed through LDS -> vt[bh][d][n]
__global__ __launch_bounds__(256) void qkvm_kernel(const ushort_t* __restrict__ xnb,
    const ushort_t* __restrict__ wqb, const float* __restrict__ bias,
    ushort_t* __restrict__ q, ushort_t* __restrict__ k, ushort_t* __restrict__ vt) {
  __shared__ __align__(16) ushort_t As[128][72];
  __shared__ __align__(16) ushort_t Bs[64][72];
  __shared__ __align__(16) ushort_t Vs[64][136];   // v transpose staging
  int j0 = blockIdx.x * 64;
  int m0 = blockIdx.y * 128;
  int tid = threadIdx.x;
  int lane = tid & 63, wv = tid >> 6;
  int l16 = lane & 15, qd = lane >> 4;
  f32x4 acc[2][4];
#pragma unroll
  for (int i=0;i<2;++i)
#pragma unroll
    for (int j=0;j<4;++j) acc[i][j] = (f32x4){0.f,0.f,0.f,0.f};
  for (int kk = 0; kk < C_; kk += 64) {
#pragma unroll
    for (int i = 0; i < 4; ++i) {
      int idx = tid + 256*i;
      int row = idx >> 3, c8 = (idx & 7) << 3;
      *(uint4*)&As[row][c8] = *(const uint4*)(xnb + (long)(m0+row)*C_ + kk + c8);
    }
    {
      int idx = tid;
      int row = idx >> 3, c8 = (idx & 7) << 3;
      *(uint4*)&Bs[row][c8] = *(const uint4*)(wqb + (long)(j0+row)*C_ + kk + c8);
      idx = tid + 256; row = idx >> 3; c8 = (idx & 7) << 3;
      *(uint4*)&Bs[row][c8] = *(const uint4*)(wqb + (long)(j0+row)*C_ + kk + c8);
    }
    __syncthreads();
#pragma unroll
    for (int kb = 0; kb < 2; ++kb) {
      int ko = kb*32 + qd*8;
      bf16x8 a0 = *(const bf16x8*)&As[wv*32 + l16][ko];
      bf16x8 a1 = *(const bf16x8*)&As[wv*32 + 16 + l16][ko];
#pragma unroll
      for (int ct = 0; ct < 4; ++ct) {
        bf16x8 b = *(const bf16x8*)&Bs[ct*16 + l16][ko];
        acc[0][ct] = __builtin_amdgcn_mfma_f32_16x16x32_bf16(a0, b, acc[0][ct], 0,0,0);
        acc[1][ct] = __builtin_amdgcn_mfma_f32_16x16x32_bf16(a1, b, acc[1][ct], 0,0,0);
      }
    }
    __syncthreads();
  }
  int three = j0 / 320;             // block-uniform
  int rembase = j0 - three*320;
  if (three < 2) {
    ushort_t* dst = three == 0 ? q : k;
    float scale = three == 0 ? 0.125f : 1.0f;
#pragma unroll
    for (int rt = 0; rt < 2; ++rt)
#pragma unroll
      for (int ct = 0; ct < 4; ++ct) {
        int rem = rembase + ct*16 + l16;
        int h = rem >> 6, dd = rem & 63;
        float bi = bias[j0 + ct*16 + l16];
#pragma unroll
        for (int r = 0; r < 4; ++r) {
          int m = m0 + wv*32 + rt*16 + qd*4 + r;
          int b = m >> 10, n = m & (N_-1);
          dst[(((long)b*H_ + h)*N_ + n)*D_ + dd] = f2b((acc[rt][ct][r] + bi) * scale);
        }
      }
  } else {
    // v: transpose via LDS so global writes are coalesced rows of vt[bh][d][n]
    int h = rembase >> 6;           // block-uniform (64-col tile within one head)
#pragma unroll
    for (int rt = 0; rt < 2; ++rt)
#pragma unroll
      for (int ct = 0; ct < 4; ++ct) {
        float bi = bias[j0 + ct*16 + l16];
#pragma unroll
        for (int r = 0; r < 4; ++r) {
          int col = wv*32 + rt*16 + qd*4 + r;     // m - m0
          Vs[ct*16 + l16][col] = f2b(acc[rt][ct][r] + bi);
        }
      }
    __syncthreads();
    int b = m0 >> 10, n0b = m0 & (N_-1);
#pragma unroll
    for (int i = 0; i < 4; ++i) {
      int idx = tid + 256*i;                      // 64 rows * 16 chunks
      int row = idx >> 4, c8 = (idx & 15) << 3;
      *(uint4*)(vt + (((long)b*H_ + h)*D_ + row)*N_ + n0b + c8) = *(const uint4*)&Vs[row][c8];
    }
  }
}

// ---------------- QK^T per (b,h) via MFMA bf16: 128x128 tile / block ----------------
__global__ __launch_bounds__(256, 4) void qk_kernel(const ushort_t* __restrict__ q,
    const ushort_t* __restrict__ kmat, ushort_t* __restrict__ attn) {
  __shared__ __align__(16) ushort_t Qs[128][72];
  __shared__ __align__(16) ushort_t Ks[128][72];
  int bh = blockIdx.z;
  int m0 = blockIdx.x * 128;   // query rows
  int n0 = blockIdx.y * 128;   // key cols
  int tid = threadIdx.x;
  int lane = tid & 63, wv = tid >> 6;
  int l16 = lane & 15, qd = lane >> 4;
  const ushort_t* qb = q    + ((long)bh*N_ + m0)*D_;
  const ushort_t* kb = kmat + ((long)bh*N_ + n0)*D_;
#pragma unroll
  for (int i = 0; i < 4; ++i) {
    int chunk = tid + 256*i;
    int row = chunk >> 3, c8 = (chunk & 7) << 3;
    *(uint4*)&Qs[row][c8] = *(const uint4*)(qb + (long)row*D_ + c8);
    *(uint4*)&Ks[row][c8] = *(const uint4*)(kb + (long)row*D_ + c8);
  }
  __syncthreads();
  f32x4 acc[2][8];
#pragma unroll
  for (int i=0;i<2;++i)
#pragma unroll
    for (int j=0;j<8;++j) acc[i][j] = (f32x4){0.f,0.f,0.f,0.f};
#pragma unroll
  for (int ks = 0; ks < 2; ++ks) {
    int k0 = ks*32 + qd*8;
    bf16x8 a0 = *(const bf16x8*)&Qs[wv*32 + l16][k0];
    bf16x8 a1 = *(const bf16x8*)&Qs[wv*32 + 16 + l16][k0];
#pragma unroll
    for (int ct = 0; ct < 8; ++ct) {
      bf16x8 b = *(const bf16x8*)&Ks[ct*16 + l16][k0];
      acc[0][ct] = __builtin_amdgcn_mfma_f32_16x16x32_bf16(a0, b, acc[0][ct], 0,0,0);
      acc[1][ct] = __builtin_amdgcn_mfma_f32_16x16x32_bf16(a1, b, acc[1][ct], 0,0,0);
    }
  }
  ushort_t* ob = attn + ((long)bh*N_ + m0 + wv*32)*N_ + n0;
#pragma unroll
  for (int rt = 0; rt < 2; ++rt)
#pragma unroll
    for (int r = 0; r < 4; ++r) {
      long rowoff = (long)(rt*16 + qd*4 + r)*N_;
#pragma unroll
      for (int ct = 0; ct < 8; ++ct)
        ob[rowoff + ct*16 + l16] = f2b(acc[rt][ct][r]);
    }
}

// ------- Fused separable blur + softmax + MFMA PV, v5 -------
// v4 -> v5: cb stored bf16, overlaid with P (one 35 KB buffer, row stride
// 1088 ushorts == bank-neutral); P group-swizzled ((m/8 + row) & 127) so the
// PV A-frag read is a perfect stride-16B pattern (v4's 18.7M conflict cycles);
// PV partials go in the dead raw buffer. LDS 145 KB -> 78 KB = 2 blocks/CU.
#define CBS 1088
__global__ __launch_bounds__(1024) void bsp_kernel(
    const ushort_t* __restrict__ attn, const ushort_t* __restrict__ vt,
    ushort_t* __restrict__ aob) {
  __shared__ __align__(16) ushort_t raw[22][1024];   // 45,056 B halo rows; later PV partials
  __shared__ __align__(16) ushort_t cbP[16][CBS];    // 34,816 B col-blur (ghost gi=m+8) then P (swizzled)
  __shared__ float redm[16][2], reds[16][2], bsum[16];

  int bh = blockIdx.y;
  int h = bh % H_;
  int bb = bh / H_;
  int n0 = blockIdx.x * TM;
  int tid = threadIdx.x;
  int lane = tid & 63;
  const ushort_t* ab = attn + (long)bh*N_*N_;

  // In-kernel Gaussian taps (sigma = h+1, alpha = 0.1*(h+1)); SGPR-pinned
  float sigma = (float)(h + 1);
  float ei = -1.f / (2.f * sigma * sigma);
  float ga = expf(9.f*ei), gb = expf(4.f*ei), gc = expf(1.f*ei);
  float isum = 1.f / (2.f*(ga + gb + gc) + 1.f);
  float alpha = 0.1f * sigma;
  float u0 = uni(ga*isum), u1 = uni(gb*isum), u2 = uni(gc*isum), u3 = uni(isum);
  float au0 = uni(alpha*u0), au1 = uni(alpha*u1), au2 = uni(alpha*u2), au3 = uni(alpha*u3);
  const float uw[7] = {u0, u1, u2, u3, u2, u1, u0};
  const float aw[7] = {au0, au1, au2, au3, au2, au1, au0};

  // ---- stage 1: load 22 halo rows (reflect) ----
#pragma unroll
  for (int i = 0; i < 3; ++i) {
    int c = tid + 1024*i;
    if (c < 2816) {
      int pr = c >> 7, c8 = (c & 127) << 3;
      int p = n0 - 3 + pr;
      int rr = p < 0 ? -p : (p > N_-1 ? 2*(N_-1)-p : p);
      *(uint4*)&raw[pr][c8] = *(const uint4*)(ab + (long)rr*N_ + c8);
    }
  }
  __syncthreads();

  // ---- stage 2: column blur -> cbP bf16 (ghost layout gi = m+8) ----
#pragma unroll
  for (int i = 0; i < 2; ++i) {
    int t = tid + 1024*i;
    int row = t >> 7, cg = t & 127;
    int m0c = cg << 3;
    float v[8] = {0.f,0.f,0.f,0.f,0.f,0.f,0.f,0.f};
#pragma unroll
    for (int dy = 0; dy < 7; ++dy) {
      uint4 rwv = *(const uint4*)&raw[row + dy][m0c];
      const ushort_t* rs = (const ushort_t*)&rwv;
      float wdy = uw[dy];
#pragma unroll
      for (int j = 0; j < 8; ++j) v[j] += wdy * b2f(rs[j]);
    }
    ushort_t pk[8];
#pragma unroll
    for (int j = 0; j < 8; ++j) pk[j] = f2b(v[j]);
    *(uint4*)&cbP[row][m0c + 8] = *(const uint4*)pk;
    if (cg == 0)   { cbP[row][7] = pk[1]; cbP[row][6] = pk[2]; cbP[row][5] = pk[3]; }
    if (cg == 127) { cbP[row][1032] = pk[6]; cbP[row][1033] = pk[5]; cbP[row][1034] = pk[4]; }
  }
  __syncthreads();

  // ---- stage 3: row blur + center -> 16 logits in registers ----
  int o = tid >> 7;
  int cg = tid & 127;
  int m0c = cg << 3;
  float lgA[8], lgB[8];
#pragma unroll
  for (int half = 0; half < 2; ++half) {
    int r = 2*o + half;
    ushort_t cs[24];
    *(uint4*)&cs[0]  = *(const uint4*)&cbP[r][m0c];
    *(uint4*)&cs[8]  = *(const uint4*)&cbP[r][m0c + 8];
    *(uint4*)&cs[16] = *(const uint4*)&cbP[r][m0c + 16];
    float cf[24];
#pragma unroll
    for (int j = 0; j < 24; ++j) cf[j] = b2f(cs[j]);
    uint4 rwv = *(const uint4*)&raw[r + 3][m0c];
    const ushort_t* rs = (const ushort_t*)&rwv;
    float* lg = half ? lgB : lgA;
#pragma unroll
    for (int j = 0; j < 8; ++j) {
      float s = b2f(rs[j]);
#pragma unroll
      for (int t = 0; t < 7; ++t) s += aw[t] * cf[5 + j + t];
      lg[j] = s;
    }
  }

  // ---- softmax ----
  float lmA = lgA[0], lmB = lgB[0];
#pragma unroll
  for (int j = 1; j < 8; ++j) { lmA = fmaxf(lmA, lgA[j]); lmB = fmaxf(lmB, lgB[j]); }
#pragma unroll
  for (int off2 = 32; off2 > 0; off2 >>= 1) {
    lmA = fmaxf(lmA, __shfl_xor(lmA, off2, 64));
    lmB = fmaxf(lmB, __shfl_xor(lmB, off2, 64));
  }
  int wv2 = (tid >> 6) & 1;
  if (lane == 0) { redm[2*o][wv2] = lmA; redm[2*o+1][wv2] = lmB; }
  __syncthreads();    // also: all cbP (cb) reads done -> safe to overwrite as P
  float bmA = fmaxf(redm[2*o][0], redm[2*o][1]);
  float bmB = fmaxf(redm[2*o+1][0], redm[2*o+1][1]);
  float smA = 0.f, smB = 0.f;
  unsigned pkA[4], pkB[4];
#pragma unroll
  for (int jj = 0; jj < 4; ++jj) {
    float eA0 = __expf(lgA[2*jj]   - bmA);
    float eA1 = __expf(lgA[2*jj+1] - bmA);
    float eB0 = __expf(lgB[2*jj]   - bmB);
    float eB1 = __expf(lgB[2*jj+1] - bmB);
    smA += eA0 + eA1; smB += eB0 + eB1;
    pkA[jj] = (unsigned)f2b(eA0) | ((unsigned)f2b(eA1) << 16);
    pkB[jj] = (unsigned)f2b(eB0) | ((unsigned)f2b(eB1) << 16);
  }
  // swizzled P store: row r, column-group g at physical group (g + r) & 127
  *(uint4*)&cbP[2*o][((cg + 2*o) & 127) << 3]     = make_uint4(pkA[0], pkA[1], pkA[2], pkA[3]);
  *(uint4*)&cbP[2*o+1][((cg + 2*o+1) & 127) << 3] = make_uint4(pkB[0], pkB[1], pkB[2], pkB[3]);
#pragma unroll
  for (int off2 = 32; off2 > 0; off2 >>= 1) {
    smA += __shfl_xor(smA, off2, 64);
    smB += __shfl_xor(smB, off2, 64);
  }
  if (lane == 0) { reds[2*o][wv2] = smA; reds[2*o+1][wv2] = smB; }
  __syncthreads();                        // P + reds visible
  if (tid < 16) bsum[tid] = reds[tid][0] + reds[tid][1];

  // ---- PV via MFMA: out[16][64] = P[16][1024] @ V[1024][64] ----
  int wv = tid >> 6;
  int dt = wv & 3, kc = wv >> 2;
  int qd = lane >> 4, l16 = lane & 15;
  f32x4 pvacc = {0.f, 0.f, 0.f, 0.f};
  const ushort_t* vtb = vt + ((long)bh*D_ + dt*16 + l16)*N_;
#pragma unroll
  for (int s = 0; s < 8; ++s) {
    int g = kc*32 + s*4 + qd;
    bf16x8 afrag = *(const bf16x8*)&cbP[l16][((g + l16) & 127) << 3];
    bf16x8 bfrag = *(const bf16x8*)(vtb + (g << 3));
    pvacc = __builtin_amdgcn_mfma_f32_16x16x32_bf16(afrag, bfrag, pvacc, 0, 0, 0);
  }
  float* pvscr = (float*)&raw[0][0];      // raw dead after stage 3
  if (kc > 0) {
    *(f32x4*)(pvscr + ((kc-1)*4 + dt)*256 + lane*4) = pvacc;
  }
  __syncthreads();                        // partials + bsum visible
  if (kc == 0) {
#pragma unroll
    for (int j = 0; j < 3; ++j) {
      f32x4 oth = *(const f32x4*)(pvscr + (j*4 + dt)*256 + lane*4);
      pvacc += oth;
    }
#pragma unroll
    for (int r = 0; r < 4; ++r) {
      int row = qd*4 + r;
      aob[((long)(bb*N_ + n0 + row))*C_ + h*64 + dt*16 + l16] = f2b(pvacc[r] / bsum[row]);
    }
  }
}

// ---------------- proj GEMM via MFMA bf16: 128(M)x64(N) tile ----------------
__global__ __launch_bounds__(256) void projm_kernel(const ushort_t* __restrict__ aob,
    const ushort_t* __restrict__ wpb, const float* __restrict__ bias,
    float* __restrict__ out) {
  __shared__ __align__(16) ushort_t As[128][72];
  __shared__ __align__(16) ushort_t Bs[64][72];
  int j0 = blockIdx.x * 64;
  int m0 = blockIdx.y * 128;
  int tid = threadIdx.x;
  int lane = tid & 63, wv = tid >> 6;
  int l16 = lane & 15, qd = lane >> 4;
  f32x4 acc[2][4];
#pragma unroll
  for (int i=0;i<2;++i)
#pragma unroll
    for (int j=0;j<4;++j) acc[i][j] = (f32x4){0.f,0.f,0.f,0.f};
  for (int kk = 0; kk < C_; kk += 64) {
#pragma unroll
    for (int i = 0; i < 4; ++i) {
      int idx = tid + 256*i;
      int row = idx >> 3, c8 = (idx & 7) << 3;
      *(uint4*)&As[row][c8] = *(const uint4*)(aob + (long)(m0+row)*C_ + kk + c8);
    }
    {
      int idx = tid;
      int row = idx >> 3, c8 = (idx & 7) << 3;
      *(uint4*)&Bs[row][c8] = *(const uint4*)(wpb + (long)(j0+row)*C_ + kk + c8);
      idx = tid + 256; row = idx >> 3; c8 = (idx & 7) << 3;
      *(uint4*)&Bs[row][c8] = *(const uint4*)(wpb + (long)(j0+row)*C_ + kk + c8);
    }
    __syncthreads();
#pragma unroll
    for (int kb = 0; kb < 2; ++kb) {
      int ko = kb*32 + qd*8;
      bf16x8 a0 = *(const bf16x8*)&As[wv*32 + l16][ko];
      bf16x8 a1 = *(const bf16x8*)&As[wv*32 + 16 + l16][ko];
#pragma unroll
      for (int ct = 0; ct < 4; ++ct) {
        bf16x8 b = *(const bf16x8*)&Bs[ct*16 + l16][ko];
        acc[0][ct] = __builtin_amdgcn_mfma_f32_16x16x32_bf16(a0, b, acc[0][ct], 0,0,0);
        acc[1][ct] = __builtin_amdgcn_mfma_f32_16x16x32_bf16(a1, b, acc[1][ct], 0,0,0);
      }
    }
    __syncthreads();
  }
#pragma unroll
  for (int rt = 0; rt < 2; ++rt)
#pragma unroll
    for (int ct = 0; ct < 4; ++ct) {
      float bi = bias[j0 + ct*16 + l16];
#pragma unroll
      for (int r = 0; r < 4; ++r) {
        int m = m0 + wv*32 + rt*16 + qd*4 + r;
        out[(long)m*C_ + j0 + ct*16 + l16] = acc[rt][ct][r] + bi;
      }
    }
}

extern "C" void kernel_launch(void* const* d_in, const int* in_sizes, int n_in,
                              void* d_out, int out_size, void* d_ws, size_t ws_size,
                              hipStream_t stream) {
  const float* x      = (const float*)d_in[0];
  const float* ln_g   = (const float*)d_in[1];
  const float* ln_b   = (const float*)d_in[2];
  const float* qkv_w  = (const float*)d_in[3];
  const float* qkv_b  = (const float*)d_in[4];
  const float* proj_w = (const float*)d_in[5];
  const float* proj_b = (const float*)d_in[6];
  float* out = (float*)d_out;

  char* ws = (char*)d_ws;
  const long sz_bhnd = (long)B_*H_*N_*D_;   // 2,621,440
  ushort_t* xnb  = (ushort_t*)ws;                   ws += (long)M_*C_*2;
  ushort_t* aob  = (ushort_t*)ws;                   ws += (long)M_*C_*2;
  ushort_t* q    = (ushort_t*)ws;                   ws += sz_bhnd*2;
  ushort_t* k    = (ushort_t*)ws;                   ws += sz_bhnd*2;
  ushort_t* vt   = (ushort_t*)ws;                   ws += sz_bhnd*2;
  ushort_t* wqb  = (ushort_t*)ws;                   ws += (long)3*C_*C_*2;
  ushort_t* wpb  = (ushort_t*)ws;                   ws += (long)C_*C_*2;
  ushort_t* attn = (ushort_t*)ws;                   // 40*1024*1024*2 B = 84 MB

  cvt_kernel<<<150, 256, 0, stream>>>(qkv_w, wqb, 3*C_*C_);
  cvt_kernel<<<50, 256, 0, stream>>>(proj_w, wpb, C_*C_);
  ln_kernel<<<M_, 64, 0, stream>>>(x, ln_g, ln_b, xnb);
  qkvm_kernel<<<dim3(15, 64), 256, 0, stream>>>(xnb, wqb, qkv_b, q, k, vt);
  qk_kernel<<<dim3(8, 8, B_*H_), 256, 0, stream>>>(q, k, attn);
  bsp_kernel<<<dim3(N_/TM, B_*H_), 1024, 0, stream>>>(attn, vt, aob);
  projm_kernel<<<dim3(5, 64), 256, 0, stream>>>(aob, wpb, proj_b, out);
}